// Round 21
// baseline (1218.194 us; speedup 1.0000x reference)
//
#include <hip/hip_runtime.h>
#include <cstdint>
#include <cstddef>

#define D_MODEL 512
#define NHEAD   8
#define DH      64
#define B_SZ    4
#define L_SEQ   2048
#define U_TOP   38          // int(5*ln(2048)) = 38
#define QPB     8           // queries per block (1 per wave)
#define KT      128         // key tile staged in LDS

// monotone float<->uint mapping (order-preserving, exact)
__device__ __forceinline__ unsigned mapmono(float f) {
    unsigned u = __float_as_uint(f);
    return (u & 0x80000000u) ? ~u : (u | 0x80000000u);
}

// ---------------- fp32 GEMM: C(8192x512) = A @ W + b ----------------
// Accurate tiled version for V and the output projection (order-insensitive).
// MODE 0: C row-major (b,l,dm)   MODE 1: scatter to (b,h,l,d)
template<int MODE>
__global__ __launch_bounds__(256)
void gemm512(const float* __restrict__ A, const float* __restrict__ W,
             const float* __restrict__ bias, float* __restrict__ C)
{
    __shared__ float As[16][68];
    __shared__ float Bs[16][68];
    const int tid  = threadIdx.x;
    const int row0 = blockIdx.x * 64;
    const int col0 = blockIdx.y * 64;
    const int ty = tid >> 4, tx = tid & 15;
    float acc[4][4] = {};

    for (int kt = 0; kt < D_MODEL; kt += 16) {
        {
            const int m = tid >> 2, k = (tid & 3) << 2;
            const float4 a = *reinterpret_cast<const float4*>(
                &A[(size_t)(row0 + m) * D_MODEL + kt + k]);
            As[k + 0][m] = a.x; As[k + 1][m] = a.y;
            As[k + 2][m] = a.z; As[k + 3][m] = a.w;
        }
        {
            const int k = tid >> 4, n = (tid & 15) << 2;
            *reinterpret_cast<float4*>(&Bs[k][n]) =
                *reinterpret_cast<const float4*>(
                    &W[(size_t)(kt + k) * D_MODEL + col0 + n]);
        }
        __syncthreads();
        #pragma unroll
        for (int kk = 0; kk < 16; ++kk) {
            const float4 a4 = *reinterpret_cast<const float4*>(&As[kk][ty << 2]);
            const float4 b4 = *reinterpret_cast<const float4*>(&Bs[kk][tx << 2]);
            const float av[4] = {a4.x, a4.y, a4.z, a4.w};
            const float bv[4] = {b4.x, b4.y, b4.z, b4.w};
            #pragma unroll
            for (int i = 0; i < 4; ++i)
                #pragma unroll
                for (int j = 0; j < 4; ++j)
                    acc[i][j] += av[i] * bv[j];
        }
        __syncthreads();
    }

    #pragma unroll
    for (int i = 0; i < 4; ++i) {
        const int r = row0 + (ty << 2) + i;
        const int cb = col0 + (tx << 2);
        float4 v;
        v.x = acc[i][0] + bias[cb + 0];
        v.y = acc[i][1] + bias[cb + 1];
        v.z = acc[i][2] + bias[cb + 2];
        v.w = acc[i][3] + bias[cb + 3];
        if (MODE == 0) {
            *reinterpret_cast<float4*>(&C[(size_t)r * D_MODEL + cb]) = v;
        } else {
            const int b = r >> 11, l = r & (L_SEQ - 1);
            const int h = cb >> 6, d = cb & 63;
            *reinterpret_cast<float4*>(
                &C[(size_t)((b * NHEAD + h) * L_SEQ + l) * DH + d]) = v;
        }
    }
}

// ----- np-replica GEMM for Q,K: SINGLE K-panel sequential FMA chain -----
// (LOCKED arithmetic — passed round 9. Per C element: ONE fp32 accumulator,
// FMA over k=0..511 ascending, then one fp32 bias add.)
__global__ __launch_bounds__(256)
void chain_gemm_qk(const float* __restrict__ x, const float* __restrict__ W,
                   const float* __restrict__ bias, float* __restrict__ Out)
{
    const int tid  = threadIdx.x;
    const int col  = blockIdx.y * 256 + tid;        // 0..511
    const int row0 = blockIdx.x * 16;               // 16 rows per block

    float acc[16];
    #pragma unroll
    for (int r = 0; r < 16; ++r) acc[r] = 0.f;

    for (int k = 0; k < D_MODEL; k += 4) {          // one panel: k = 0..511
        const float w0 = W[(size_t)(k + 0) * D_MODEL + col];
        const float w1 = W[(size_t)(k + 1) * D_MODEL + col];
        const float w2 = W[(size_t)(k + 2) * D_MODEL + col];
        const float w3 = W[(size_t)(k + 3) * D_MODEL + col];
        #pragma unroll
        for (int r = 0; r < 16; ++r) {
            const float4 xv = *reinterpret_cast<const float4*>(
                &x[(size_t)(row0 + r) * D_MODEL + k]);
            acc[r] = __fmaf_rn(xv.x, w0, acc[r]);
            acc[r] = __fmaf_rn(xv.y, w1, acc[r]);
            acc[r] = __fmaf_rn(xv.z, w2, acc[r]);
            acc[r] = __fmaf_rn(xv.w, w3, acc[r]);
        }
    }

    const float bc = bias[col];
    const int h = col >> 6, d = col & 63;
    #pragma unroll
    for (int r = 0; r < 16; ++r) {
        const int row = row0 + r;
        const int b = row >> 11, l = row & (L_SEQ - 1);
        Out[((size_t)((b * NHEAD + h) * L_SEQ + l)) * DH + d] =
            __fadd_rn(acc[r], bc);
    }
}

// ---- attention: BLAS-chain scores (LOCKED bits) -> exact fp32 top-38 ----
// r21 = r14 + two additive, arithmetic-neutral changes:
//  * Q via SCALAR loads (readfirstlane row index -> s_load_dwordx4 from
//    global, K$-resident): removes 256 of 768 ds_read_b128/wave (-33%
//    LDS-port traffic, the measured binding resource) + deletes Qs LDS
//  * binary search bounds narrowed to [rowmin, rowmax+1]: same invariant
//    (count>=38 at lo, <38 at hi), identical result, ~7 fewer iterations
// Ledger (rejected by measurement): 2q/wave regs (spill), 2q LDS-spill /
// dbuf (70KB -> 24% occ), K-from-global (uncoalesced VMEM).
__global__ __launch_bounds__(512, 4)
void attn_kernel(const float* __restrict__ Q, const float* __restrict__ K,
                 const float* __restrict__ V, float* __restrict__ ctx)
{
    __shared__ float Ks[KT * DH];          // 32 KB, elem = r*64 + (col ^ ((r&7)<<2))
    __shared__ int   kidx[QPB][64];        // 2 KB  kept keys (ascending)
    __shared__ float kwgt[QPB][64];        // 2 KB  kept exp-weights

    // XCD swizzle: all 256 q-tiles of a (b,h) on one XCD (K/V L2-resident)
    const int bid = blockIdx.x;
    const int xcd = bid & 7, jrem = bid >> 3;
    const int bh  = xcd * 4 + (jrem >> 8);   // 0..31
    const int qt  = jrem & 255;              // 0..255
    const int b   = bh >> 3, h = bh & 7;

    const float* __restrict__ Qbh = Q + (size_t)bh * L_SEQ * DH;
    const float* __restrict__ Kbh = K + (size_t)bh * L_SEQ * DH;
    const float* __restrict__ Vbh = V + (size_t)bh * L_SEQ * DH;

    const int tid = threadIdx.x;
    const int wave = tid >> 6, lane = tid & 63;
    const int qg = wave;                     // one query per wave

    // wave-uniform Q row pointer, forced scalar -> s_load path
    const int qrow = __builtin_amdgcn_readfirstlane(qt * QPB + wave);
    const float* __restrict__ Qp = Qbh + (size_t)qrow * DH;

    float s[32];

    #pragma unroll
    for (int t = 0; t < L_SEQ / KT; ++t) {        // 16 tiles, fully unrolled
        __syncthreads();
        #pragma unroll
        for (int c = 0; c < 4; ++c) {             // stage K tile, swizzled
            const int f = c * 2048 + tid * 4;
            const int r = f >> 6, col = f & 63;
            const int sidx = (r << 6) + (col ^ ((r & 7) << 2));
            *reinterpret_cast<float4*>(&Ks[sidx]) =
                *reinterpret_cast<const float4*>(&Kbh[(size_t)t * (KT * DH) + f]);
        }
        __syncthreads();

        // single FMA chain over d ascending per key — LOCKED order
        float v0 = 0.f, v1 = 0.f;
        #pragma unroll
        for (int dc = 0; dc < 16; ++dc) {
            const int sw = (dc ^ (lane & 7)) << 2;   // logical cols 4dc..4dc+3
            const float4 k0 = *reinterpret_cast<const float4*>(
                &Ks[(lane << 6) + sw]);
            const float4 k1 = *reinterpret_cast<const float4*>(
                &Ks[((64 + lane) << 6) + sw]);
            const float4 p = *reinterpret_cast<const float4*>(&Qp[dc << 2]);
            v0 = __fmaf_rn(p.x, k0.x, v0);
            v0 = __fmaf_rn(p.y, k0.y, v0);
            v0 = __fmaf_rn(p.z, k0.z, v0);
            v0 = __fmaf_rn(p.w, k0.w, v0);
            v1 = __fmaf_rn(p.x, k1.x, v1);
            v1 = __fmaf_rn(p.y, k1.y, v1);
            v1 = __fmaf_rn(p.z, k1.z, v1);
            v1 = __fmaf_rn(p.w, k1.w, v1);
        }
        // /sqrt(64) = *0.125, exact
        s[2*t]     = __fmul_rn(v0, 0.125f);
        s[2*t + 1] = __fmul_rn(v1, 0.125f);
    }

    // map scores to monotone uint space (in place)
    #pragma unroll
    for (int j = 0; j < 32; ++j)
        s[j] = __uint_as_float(mapmono(s[j]));

    // row max AND min in mapped space (max -> mrow; both -> search bounds)
    unsigned um = 0u, umin = 0xFFFFFFFFu;
    #pragma unroll
    for (int j = 0; j < 32; ++j) {
        const unsigned ub = __float_as_uint(s[j]);
        um   = um > ub ? um : ub;
        umin = umin < ub ? umin : ub;
    }
    #pragma unroll
    for (int off = 32; off; off >>= 1) {
        const unsigned o  = (unsigned)__shfl_xor((int)um, off);
        const unsigned o2 = (unsigned)__shfl_xor((int)umin, off);
        um   = um > o ? um : o;
        umin = umin < o2 ? umin : o2;
    }
    const float mrow = __uint_as_float((um & 0x80000000u) ? (um & 0x7FFFFFFFu) : ~um);

    // exact fp32 38th-largest: binary search on [min, max+1] (invariant:
    // count(u>=lo)>=38 [=2048], count(u>=hi)<38 [=0]) — identical result.
    unsigned long long lo = umin, hi = (unsigned long long)um + 1ull;
    while (hi - lo > 1ull) {
        const unsigned mid = (unsigned)((lo + hi) >> 1);
        int cnt = 0;
        #pragma unroll
        for (int j = 0; j < 32; ++j)
            cnt += (int)__popcll(__ballot(__float_as_uint(s[j]) >= mid));
        if (cnt >= U_TOP) lo = mid; else hi = mid;
    }
    const unsigned thrU = (unsigned)lo;     // mapped bits of the 38th value

    // compact kept keys (ascending key order) via ballot prefix-sum
    int base = 0; float lsum = 0.f;
    #pragma unroll
    for (int j = 0; j < 32; ++j) {
        const unsigned ub = __float_as_uint(s[j]);
        const bool keep = (ub >= thrU);     // == !(score < thr), np semantics
        const unsigned long long mk = __ballot(keep);
        if (keep) {
            const float sc = __uint_as_float((ub & 0x80000000u) ? (ub & 0x7FFFFFFFu) : ~ub);
            const float w = __expf(sc - mrow);
            const int pos = base + (int)__popcll(mk & ((1ull << lane) - 1ull));
            if (pos < 64) {
                kidx[qg][pos] = ((j >> 1) << 7) + ((j & 1) << 6) + lane;
                kwgt[qg][pos] = w;
            }
            lsum += w;
        }
        base += (int)__popcll(mk);
    }
    #pragma unroll
    for (int off = 32; off; off >>= 1) lsum += __shfl_xor(lsum, off);
    const int nk = base < 64 ? base : 64;

    // ctx[d] = (sum over kept, ascending key order) w * V[k][d] / Z
    // 8-deep load pipeline; FMA chain order preserved (ascending i)
    float acc = 0.f;
    int i = 0;
    for (; i + 8 <= nk; i += 8) {
        float wv[8], vv[8];
        #pragma unroll
        for (int u = 0; u < 8; ++u) {
            wv[u] = kwgt[qg][i + u];
            vv[u] = Vbh[(size_t)kidx[qg][i + u] * DH + lane];
        }
        #pragma unroll
        for (int u = 0; u < 8; ++u)
            acc = __fmaf_rn(wv[u], vv[u], acc);
    }
    for (; i < nk; ++i)
        acc = __fmaf_rn(kwgt[qg][i], Vbh[(size_t)kidx[qg][i] * DH + lane], acc);
    acc /= lsum;

    const int l = qt * QPB + qg;
    ctx[((size_t)(b * L_SEQ + l)) * D_MODEL + h * DH + lane] = acc;
}

extern "C" void kernel_launch(void* const* d_in, const int* in_sizes, int n_in,
                              void* d_out, int out_size, void* d_ws, size_t ws_size,
                              hipStream_t stream) {
    (void)in_sizes; (void)n_in; (void)out_size; (void)ws_size;
    const float* x  = (const float*)d_in[0];
    const float* Wq = (const float*)d_in[1];
    const float* bq = (const float*)d_in[2];
    const float* Wk = (const float*)d_in[3];
    const float* bk = (const float*)d_in[4];
    const float* Wv = (const float*)d_in[5];
    const float* bv = (const float*)d_in[6];
    const float* Wo = (const float*)d_in[7];
    const float* bo = (const float*)d_in[8];
    float* out = (float*)d_out;

    // ws: Qf | Kf | V | ctx = 4 x 16.78 MB = 67.1 MB
    const size_t NE = (size_t)B_SZ * NHEAD * L_SEQ * DH;   // 4.19e6
    float* Qf = (float*)d_ws;
    float* Kf = Qf + NE;
    float* Vw = Kf + NE;
    float* Cw = Vw + NE;

    const dim3 gq(512, 2), g(128, 8), blk(256);
    chain_gemm_qk<<<gq, blk, 0, stream>>>(x, Wq, bq, Qf);
    chain_gemm_qk<<<gq, blk, 0, stream>>>(x, Wk, bk, Kf);
    gemm512<1>   <<<g,  blk, 0, stream>>>(x, Wv, bv, Vw);
    attn_kernel  <<<dim3(8192), dim3(512), 0, stream>>>(Qf, Kf, Vw, Cw);
    gemm512<0>   <<<g,  blk, 0, stream>>>(Cw, Wo, bo, out);
}

// Round 22
// 1132.303 us; speedup vs baseline: 1.0759x; 1.0759x over previous
//
#include <hip/hip_runtime.h>
#include <cstdint>
#include <cstddef>

#define D_MODEL 512
#define NHEAD   8
#define DH      64
#define B_SZ    4
#define L_SEQ   2048
#define U_TOP   38          // int(5*ln(2048)) = 38
#define QPB     8           // queries per block (1 per wave)
#define KT      128         // key tile staged in LDS

// monotone float<->uint mapping (order-preserving, exact)
__device__ __forceinline__ unsigned mapmono(float f) {
    unsigned u = __float_as_uint(f);
    return (u & 0x80000000u) ? ~u : (u | 0x80000000u);
}

typedef __attribute__((address_space(1))) const float gas_float;
typedef __attribute__((address_space(3))) float las_float;

// ---------------- fp32 GEMM: C(8192x512) = A @ W + b ----------------
// Accurate tiled version for V and the output projection (order-insensitive).
// MODE 0: C row-major (b,l,dm)   MODE 1: scatter to (b,h,l,d)
template<int MODE>
__global__ __launch_bounds__(256)
void gemm512(const float* __restrict__ A, const float* __restrict__ W,
             const float* __restrict__ bias, float* __restrict__ C)
{
    __shared__ float As[16][68];
    __shared__ float Bs[16][68];
    const int tid  = threadIdx.x;
    const int row0 = blockIdx.x * 64;
    const int col0 = blockIdx.y * 64;
    const int ty = tid >> 4, tx = tid & 15;
    float acc[4][4] = {};

    for (int kt = 0; kt < D_MODEL; kt += 16) {
        {
            const int m = tid >> 2, k = (tid & 3) << 2;
            const float4 a = *reinterpret_cast<const float4*>(
                &A[(size_t)(row0 + m) * D_MODEL + kt + k]);
            As[k + 0][m] = a.x; As[k + 1][m] = a.y;
            As[k + 2][m] = a.z; As[k + 3][m] = a.w;
        }
        {
            const int k = tid >> 4, n = (tid & 15) << 2;
            *reinterpret_cast<float4*>(&Bs[k][n]) =
                *reinterpret_cast<const float4*>(
                    &W[(size_t)(kt + k) * D_MODEL + col0 + n]);
        }
        __syncthreads();
        #pragma unroll
        for (int kk = 0; kk < 16; ++kk) {
            const float4 a4 = *reinterpret_cast<const float4*>(&As[kk][ty << 2]);
            const float4 b4 = *reinterpret_cast<const float4*>(&Bs[kk][tx << 2]);
            const float av[4] = {a4.x, a4.y, a4.z, a4.w};
            const float bv[4] = {b4.x, b4.y, b4.z, b4.w};
            #pragma unroll
            for (int i = 0; i < 4; ++i)
                #pragma unroll
                for (int j = 0; j < 4; ++j)
                    acc[i][j] += av[i] * bv[j];
        }
        __syncthreads();
    }

    #pragma unroll
    for (int i = 0; i < 4; ++i) {
        const int r = row0 + (ty << 2) + i;
        const int cb = col0 + (tx << 2);
        float4 v;
        v.x = acc[i][0] + bias[cb + 0];
        v.y = acc[i][1] + bias[cb + 1];
        v.z = acc[i][2] + bias[cb + 2];
        v.w = acc[i][3] + bias[cb + 3];
        if (MODE == 0) {
            *reinterpret_cast<float4*>(&C[(size_t)r * D_MODEL + cb]) = v;
        } else {
            const int b = r >> 11, l = r & (L_SEQ - 1);
            const int h = cb >> 6, d = cb & 63;
            *reinterpret_cast<float4*>(
                &C[(size_t)((b * NHEAD + h) * L_SEQ + l) * DH + d]) = v;
        }
    }
}

// ----- np-replica GEMM for Q,K: SINGLE K-panel sequential FMA chain -----
// (LOCKED arithmetic — passed round 9. Per C element: ONE fp32 accumulator,
// FMA over k=0..511 ascending, then one fp32 bias add.)
// Fused: blockIdx.z = 0 -> (Wq,bq,OutQ), 1 -> (Wk,bk,OutK).
__global__ __launch_bounds__(256)
void chain_gemm_qk(const float* __restrict__ x,
                   const float* __restrict__ Wq, const float* __restrict__ bq,
                   float* __restrict__ OutQ,
                   const float* __restrict__ Wk, const float* __restrict__ bk,
                   float* __restrict__ OutK)
{
    const float* __restrict__ W    = blockIdx.z ? Wk : Wq;
    const float* __restrict__ bias = blockIdx.z ? bk : bq;
    float* __restrict__ Out        = blockIdx.z ? OutK : OutQ;

    const int tid  = threadIdx.x;
    const int col  = blockIdx.y * 256 + tid;        // 0..511
    const int row0 = blockIdx.x * 16;               // 16 rows per block

    float acc[16];
    #pragma unroll
    for (int r = 0; r < 16; ++r) acc[r] = 0.f;

    for (int k = 0; k < D_MODEL; k += 4) {          // one panel: k = 0..511
        const float w0 = W[(size_t)(k + 0) * D_MODEL + col];
        const float w1 = W[(size_t)(k + 1) * D_MODEL + col];
        const float w2 = W[(size_t)(k + 2) * D_MODEL + col];
        const float w3 = W[(size_t)(k + 3) * D_MODEL + col];
        #pragma unroll
        for (int r = 0; r < 16; ++r) {
            const float4 xv = *reinterpret_cast<const float4*>(
                &x[(size_t)(row0 + r) * D_MODEL + k]);
            acc[r] = __fmaf_rn(xv.x, w0, acc[r]);
            acc[r] = __fmaf_rn(xv.y, w1, acc[r]);
            acc[r] = __fmaf_rn(xv.z, w2, acc[r]);
            acc[r] = __fmaf_rn(xv.w, w3, acc[r]);
        }
    }

    const float bc = bias[col];
    const int h = col >> 6, d = col & 63;
    #pragma unroll
    for (int r = 0; r < 16; ++r) {
        const int row = row0 + r;
        const int b = row >> 11, l = row & (L_SEQ - 1);
        Out[((size_t)((b * NHEAD + h) * L_SEQ + l)) * DH + d] =
            __fadd_rn(acc[r], bc);
    }
}

// ---- attention: BLAS-chain scores (LOCKED bits) -> exact fp32 top-38 ----
// r22 = r21 + global_load_lds staging (arithmetic bit-identical):
//  * K tile staged via __builtin_amdgcn_global_load_lds width=16: direct
//    global->LDS DMA, no VGPR transit, no ds_write, single vmcnt drain at
//    the barrier (removes the exposed vm-wait->lgkm-wait chain per tile
//    = the ~38% non-VALU stall time). Swizzled layout kept via
//    PRE-SWIZZLED global source + linear LDS dest (m173; r16/r17-proven).
//    LDS dest passed as wave-uniform base (HW adds lane*16, m104).
//  * VGPR budget: MUST stay <=64 (m69 cliff; explains r16/r17/r18's 24%
//    occupancy at 88-128 VGPR vs r14/r21's 46% at 60-64).
__global__ __launch_bounds__(512, 4)
void attn_kernel(const float* __restrict__ Q, const float* __restrict__ K,
                 const float* __restrict__ V, float* __restrict__ ctx)
{
    __shared__ float Ks[KT * DH];          // 32 KB, slot s holds
                                           // K[s>>6][(s&63)^(((s>>6)&7)<<2)]
    __shared__ int   kidx[QPB][64];        // 2 KB  kept keys (ascending)
    __shared__ float kwgt[QPB][64];        // 2 KB  kept exp-weights

    // XCD swizzle: all 256 q-tiles of a (b,h) on one XCD (K/V L2-resident)
    const int bid = blockIdx.x;
    const int xcd = bid & 7, jrem = bid >> 3;
    const int bh  = xcd * 4 + (jrem >> 8);   // 0..31
    const int qt  = jrem & 255;              // 0..255
    const int b   = bh >> 3, h = bh & 7;

    const float* __restrict__ Qbh = Q + (size_t)bh * L_SEQ * DH;
    const float* __restrict__ Kbh = K + (size_t)bh * L_SEQ * DH;
    const float* __restrict__ Vbh = V + (size_t)bh * L_SEQ * DH;

    const int tid = threadIdx.x;
    const int wave = tid >> 6, lane = tid & 63;
    const int qg = wave;                     // one query per wave

    // wave-uniform Q row pointer, forced scalar -> s_load path
    const int qrow = __builtin_amdgcn_readfirstlane(qt * QPB + wave);
    const float* __restrict__ Qp = Qbh + (size_t)qrow * DH;

    // pre-swizzled global source offsets (tile-invariant, 4 chunks) and
    // wave-uniform LDS chunk bases (lane*16B added by HW)
    int soff[4];
    #pragma unroll
    for (int c = 0; c < 4; ++c) {
        const int f = c * 2048 + tid * 4;
        const int r = f >> 6, col = f & 63;
        soff[c] = (r << 6) + (col ^ ((r & 7) << 2));
    }

    float s[32];

    #pragma unroll
    for (int t = 0; t < L_SEQ / KT; ++t) {        // 16 tiles, fully unrolled
        __syncthreads();                           // Ks safe to overwrite
        const float* src = Kbh + (size_t)t * (KT * DH);
        #pragma unroll
        for (int c = 0; c < 4; ++c) {              // direct global->LDS DMA
            __builtin_amdgcn_global_load_lds(
                (gas_float*)(src + soff[c]),
                (las_float*)&Ks[c * 2048 + wave * 256],
                16, 0, 0);
        }
        __syncthreads();                           // vmcnt drained here

        // single FMA chain over d ascending per key — LOCKED order
        float v0 = 0.f, v1 = 0.f;
        #pragma unroll
        for (int dc = 0; dc < 16; ++dc) {
            const int sw = (dc ^ (lane & 7)) << 2;   // logical cols 4dc..4dc+3
            const float4 k0 = *reinterpret_cast<const float4*>(
                &Ks[(lane << 6) + sw]);
            const float4 k1 = *reinterpret_cast<const float4*>(
                &Ks[((64 + lane) << 6) + sw]);
            const float4 p = *reinterpret_cast<const float4*>(&Qp[dc << 2]);
            v0 = __fmaf_rn(p.x, k0.x, v0);
            v0 = __fmaf_rn(p.y, k0.y, v0);
            v0 = __fmaf_rn(p.z, k0.z, v0);
            v0 = __fmaf_rn(p.w, k0.w, v0);
            v1 = __fmaf_rn(p.x, k1.x, v1);
            v1 = __fmaf_rn(p.y, k1.y, v1);
            v1 = __fmaf_rn(p.z, k1.z, v1);
            v1 = __fmaf_rn(p.w, k1.w, v1);
        }
        // /sqrt(64) = *0.125, exact
        s[2*t]     = __fmul_rn(v0, 0.125f);
        s[2*t + 1] = __fmul_rn(v1, 0.125f);
    }

    // map scores to monotone uint space (in place)
    #pragma unroll
    for (int j = 0; j < 32; ++j)
        s[j] = __uint_as_float(mapmono(s[j]));

    // row max AND min in mapped space (max -> mrow; both -> search bounds)
    unsigned um = 0u, umin = 0xFFFFFFFFu;
    #pragma unroll
    for (int j = 0; j < 32; ++j) {
        const unsigned ub = __float_as_uint(s[j]);
        um   = um > ub ? um : ub;
        umin = umin < ub ? umin : ub;
    }
    #pragma unroll
    for (int off = 32; off; off >>= 1) {
        const unsigned o  = (unsigned)__shfl_xor((int)um, off);
        const unsigned o2 = (unsigned)__shfl_xor((int)umin, off);
        um   = um > o ? um : o;
        umin = umin < o2 ? umin : o2;
    }
    const float mrow = __uint_as_float((um & 0x80000000u) ? (um & 0x7FFFFFFFu) : ~um);

    // exact fp32 38th-largest: binary search on [min, max+1] (invariant:
    // count(u>=lo)>=38 [=2048], count(u>=hi)<38 [=0]) — identical result.
    unsigned long long lo = umin, hi = (unsigned long long)um + 1ull;
    while (hi - lo > 1ull) {
        const unsigned mid = (unsigned)((lo + hi) >> 1);
        int cnt = 0;
        #pragma unroll
        for (int j = 0; j < 32; ++j)
            cnt += (int)__popcll(__ballot(__float_as_uint(s[j]) >= mid));
        if (cnt >= U_TOP) lo = mid; else hi = mid;
    }
    const unsigned thrU = (unsigned)lo;     // mapped bits of the 38th value

    // compact kept keys (ascending key order) via ballot prefix-sum
    int base = 0; float lsum = 0.f;
    #pragma unroll
    for (int j = 0; j < 32; ++j) {
        const unsigned ub = __float_as_uint(s[j]);
        const bool keep = (ub >= thrU);     // == !(score < thr), np semantics
        const unsigned long long mk = __ballot(keep);
        if (keep) {
            const float sc = __uint_as_float((ub & 0x80000000u) ? (ub & 0x7FFFFFFFu) : ~ub);
            const float w = __expf(sc - mrow);
            const int pos = base + (int)__popcll(mk & ((1ull << lane) - 1ull));
            if (pos < 64) {
                kidx[qg][pos] = ((j >> 1) << 7) + ((j & 1) << 6) + lane;
                kwgt[qg][pos] = w;
            }
            lsum += w;
        }
        base += (int)__popcll(mk);
    }
    #pragma unroll
    for (int off = 32; off; off >>= 1) lsum += __shfl_xor(lsum, off);
    const int nk = base < 64 ? base : 64;

    // ctx[d] = (sum over kept, ascending key order) w * V[k][d] / Z
    // 8-deep load pipeline; FMA chain order preserved (ascending i)
    float acc = 0.f;
    int i = 0;
    for (; i + 8 <= nk; i += 8) {
        float wv[8], vv[8];
        #pragma unroll
        for (int u = 0; u < 8; ++u) {
            wv[u] = kwgt[qg][i + u];
            vv[u] = Vbh[(size_t)kidx[qg][i + u] * DH + lane];
        }
        #pragma unroll
        for (int u = 0; u < 8; ++u)
            acc = __fmaf_rn(wv[u], vv[u], acc);
    }
    for (; i < nk; ++i)
        acc = __fmaf_rn(kwgt[qg][i], Vbh[(size_t)kidx[qg][i] * DH + lane], acc);
    acc /= lsum;

    const int l = qt * QPB + qg;
    ctx[((size_t)(b * L_SEQ + l)) * D_MODEL + h * DH + lane] = acc;
}

extern "C" void kernel_launch(void* const* d_in, const int* in_sizes, int n_in,
                              void* d_out, int out_size, void* d_ws, size_t ws_size,
                              hipStream_t stream) {
    (void)in_sizes; (void)n_in; (void)out_size; (void)ws_size;
    const float* x  = (const float*)d_in[0];
    const float* Wq = (const float*)d_in[1];
    const float* bq = (const float*)d_in[2];
    const float* Wk = (const float*)d_in[3];
    const float* bk = (const float*)d_in[4];
    const float* Wv = (const float*)d_in[5];
    const float* bv = (const float*)d_in[6];
    const float* Wo = (const float*)d_in[7];
    const float* bo = (const float*)d_in[8];
    float* out = (float*)d_out;

    // ws: Qf | Kf | V | ctx = 4 x 16.78 MB = 67.1 MB
    const size_t NE = (size_t)B_SZ * NHEAD * L_SEQ * DH;   // 4.19e6
    float* Qf = (float*)d_ws;
    float* Kf = Qf + NE;
    float* Vw = Kf + NE;
    float* Cw = Vw + NE;

    const dim3 gqk(512, 2, 2), g(128, 8), blk(256);
    chain_gemm_qk<<<gqk, blk, 0, stream>>>(x, Wq, bq, Qf, Wk, bk, Kf);
    gemm512<1>   <<<g,   blk, 0, stream>>>(x, Wv, bv, Vw);
    attn_kernel  <<<dim3(8192), dim3(512), 0, stream>>>(Qf, Kf, Vw, Cw);
    gemm512<0>   <<<g,   blk, 0, stream>>>(Cw, Wo, bo, out);
}

// Round 23
// 1102.948 us; speedup vs baseline: 1.1045x; 1.0266x over previous
//
#include <hip/hip_runtime.h>
#include <cstdint>
#include <cstddef>

#define D_MODEL 512
#define NHEAD   8
#define DH      64
#define B_SZ    4
#define L_SEQ   2048
#define U_TOP   38          // int(5*ln(2048)) = 38
#define QPB     8           // queries per block (1 per wave)
#define KT      128         // key tile staged in LDS
#define TILE_DW (KT * DH)   // 8192 dwords

// monotone float<->uint mapping (order-preserving, exact)
__device__ __forceinline__ unsigned mapmono(float f) {
    unsigned u = __float_as_uint(f);
    return (u & 0x80000000u) ? ~u : (u | 0x80000000u);
}

typedef __attribute__((address_space(1))) const float gas_float;
typedef __attribute__((address_space(3))) float las_float;

// ---------------- fp32 GEMM: C(8192x512) = A @ W + b ----------------
// Accurate tiled version for V and the output projection (order-insensitive).
// MODE 0: C row-major (b,l,dm)   MODE 1: scatter to (b,h,l,d)
template<int MODE>
__global__ __launch_bounds__(256)
void gemm512(const float* __restrict__ A, const float* __restrict__ W,
             const float* __restrict__ bias, float* __restrict__ C)
{
    __shared__ float As[16][68];
    __shared__ float Bs[16][68];
    const int tid  = threadIdx.x;
    const int row0 = blockIdx.x * 64;
    const int col0 = blockIdx.y * 64;
    const int ty = tid >> 4, tx = tid & 15;
    float acc[4][4] = {};

    for (int kt = 0; kt < D_MODEL; kt += 16) {
        {
            const int m = tid >> 2, k = (tid & 3) << 2;
            const float4 a = *reinterpret_cast<const float4*>(
                &A[(size_t)(row0 + m) * D_MODEL + kt + k]);
            As[k + 0][m] = a.x; As[k + 1][m] = a.y;
            As[k + 2][m] = a.z; As[k + 3][m] = a.w;
        }
        {
            const int k = tid >> 4, n = (tid & 15) << 2;
            *reinterpret_cast<float4*>(&Bs[k][n]) =
                *reinterpret_cast<const float4*>(
                    &W[(size_t)(kt + k) * D_MODEL + col0 + n]);
        }
        __syncthreads();
        #pragma unroll
        for (int kk = 0; kk < 16; ++kk) {
            const float4 a4 = *reinterpret_cast<const float4*>(&As[kk][ty << 2]);
            const float4 b4 = *reinterpret_cast<const float4*>(&Bs[kk][tx << 2]);
            const float av[4] = {a4.x, a4.y, a4.z, a4.w};
            const float bv[4] = {b4.x, b4.y, b4.z, b4.w};
            #pragma unroll
            for (int i = 0; i < 4; ++i)
                #pragma unroll
                for (int j = 0; j < 4; ++j)
                    acc[i][j] += av[i] * bv[j];
        }
        __syncthreads();
    }

    #pragma unroll
    for (int i = 0; i < 4; ++i) {
        const int r = row0 + (ty << 2) + i;
        const int cb = col0 + (tx << 2);
        float4 v;
        v.x = acc[i][0] + bias[cb + 0];
        v.y = acc[i][1] + bias[cb + 1];
        v.z = acc[i][2] + bias[cb + 2];
        v.w = acc[i][3] + bias[cb + 3];
        if (MODE == 0) {
            *reinterpret_cast<float4*>(&C[(size_t)r * D_MODEL + cb]) = v;
        } else {
            const int b = r >> 11, l = r & (L_SEQ - 1);
            const int h = cb >> 6, d = cb & 63;
            *reinterpret_cast<float4*>(
                &C[(size_t)((b * NHEAD + h) * L_SEQ + l) * DH + d]) = v;
        }
    }
}

// ----- np-replica GEMM for Q,K: SINGLE K-panel sequential FMA chain -----
// (LOCKED arithmetic — passed round 9. Per C element: ONE fp32 accumulator,
// FMA over k=0..511 ascending, then one fp32 bias add.)
// Fused: blockIdx.z = 0 -> (Wq,bq,OutQ), 1 -> (Wk,bk,OutK).
__global__ __launch_bounds__(256)
void chain_gemm_qk(const float* __restrict__ x,
                   const float* __restrict__ Wq, const float* __restrict__ bq,
                   float* __restrict__ OutQ,
                   const float* __restrict__ Wk, const float* __restrict__ bk,
                   float* __restrict__ OutK)
{
    const float* __restrict__ W    = blockIdx.z ? Wk : Wq;
    const float* __restrict__ bias = blockIdx.z ? bk : bq;
    float* __restrict__ Out        = blockIdx.z ? OutK : OutQ;

    const int tid  = threadIdx.x;
    const int col  = blockIdx.y * 256 + tid;        // 0..511
    const int row0 = blockIdx.x * 16;               // 16 rows per block

    float acc[16];
    #pragma unroll
    for (int r = 0; r < 16; ++r) acc[r] = 0.f;

    for (int k = 0; k < D_MODEL; k += 4) {          // one panel: k = 0..511
        const float w0 = W[(size_t)(k + 0) * D_MODEL + col];
        const float w1 = W[(size_t)(k + 1) * D_MODEL + col];
        const float w2 = W[(size_t)(k + 2) * D_MODEL + col];
        const float w3 = W[(size_t)(k + 3) * D_MODEL + col];
        #pragma unroll
        for (int r = 0; r < 16; ++r) {
            const float4 xv = *reinterpret_cast<const float4*>(
                &x[(size_t)(row0 + r) * D_MODEL + k]);
            acc[r] = __fmaf_rn(xv.x, w0, acc[r]);
            acc[r] = __fmaf_rn(xv.y, w1, acc[r]);
            acc[r] = __fmaf_rn(xv.z, w2, acc[r]);
            acc[r] = __fmaf_rn(xv.w, w3, acc[r]);
        }
    }

    const float bc = bias[col];
    const int h = col >> 6, d = col & 63;
    #pragma unroll
    for (int r = 0; r < 16; ++r) {
        const int row = row0 + r;
        const int b = row >> 11, l = row & (L_SEQ - 1);
        Out[((size_t)((b * NHEAD + h) * L_SEQ + l)) * DH + d] =
            __fadd_rn(acc[r], bc);
    }
}

// ---- attention: BLAS-chain scores (LOCKED bits) -> exact fp32 top-38 ----
// r23 = r22 + double-buffered global_load_lds (arithmetic bit-identical):
//  * tile t+1's DMA issued BEFORE compute of tile t (other buffer); the
//    compiler's vmcnt(0) drain at the single per-tile barrier then lands
//    AFTER a full compute phase covered the DMA latency (r22's flow was
//    barrier->DMA->barrier with the ~600cyc DMA fully exposed = the 33%
//    idle). VGPR stays ~60 (no transit regs; unrolled -> static addrs),
//    unlike r18's reg-staged dbuf (88 VGPR, over the 64-cliff).
//  * LDS 68.6KB -> 2 blocks/CU = 16 waves = current measured residency.
//  Race audit: loads(t+1)->buf^1 overlap reads of buf; buf^1's readers
//  finished before the previous barrier; loads(t) drained before compute(t).
__global__ __launch_bounds__(512, 4)
void attn_kernel(const float* __restrict__ Q, const float* __restrict__ K,
                 const float* __restrict__ V, float* __restrict__ ctx)
{
    __shared__ float Ks[2 * TILE_DW];      // 64 KB dbuf; slot s of each buf
                                           // holds K[s>>6][(s&63)^(((s>>6)&7)<<2)]
    __shared__ int   kidx[QPB][64];        // 2 KB  kept keys (ascending)
    __shared__ float kwgt[QPB][64];        // 2 KB  kept exp-weights

    // XCD swizzle: all 256 q-tiles of a (b,h) on one XCD (K/V L2-resident)
    const int bid = blockIdx.x;
    const int xcd = bid & 7, jrem = bid >> 3;
    const int bh  = xcd * 4 + (jrem >> 8);   // 0..31
    const int qt  = jrem & 255;              // 0..255
    const int b   = bh >> 3, h = bh & 7;

    const float* __restrict__ Qbh = Q + (size_t)bh * L_SEQ * DH;
    const float* __restrict__ Kbh = K + (size_t)bh * L_SEQ * DH;
    const float* __restrict__ Vbh = V + (size_t)bh * L_SEQ * DH;

    const int tid = threadIdx.x;
    const int wave = tid >> 6, lane = tid & 63;
    const int qg = wave;                     // one query per wave

    // wave-uniform Q row pointer, forced scalar -> s_load path
    const int qrow = __builtin_amdgcn_readfirstlane(qt * QPB + wave);
    const float* __restrict__ Qp = Qbh + (size_t)qrow * DH;

    // pre-swizzled global source offsets (tile-invariant, 4 chunks)
    int soff[4];
    #pragma unroll
    for (int c = 0; c < 4; ++c) {
        const int f = c * 2048 + tid * 4;
        const int r = f >> 6, col = f & 63;
        soff[c] = (r << 6) + (col ^ ((r & 7) << 2));
    }

    // prologue: DMA tile 0 into buf0, publish
    #pragma unroll
    for (int c = 0; c < 4; ++c)
        __builtin_amdgcn_global_load_lds(
            (gas_float*)(Kbh + soff[c]),
            (las_float*)&Ks[c * 2048 + wave * 256], 16, 0, 0);
    __syncthreads();

    float s[32];

    #pragma unroll
    for (int t = 0; t < L_SEQ / KT; ++t) {        // 16 tiles, fully unrolled
        const float* buf = &Ks[(t & 1) * TILE_DW];

        if (t < L_SEQ / KT - 1) {                  // issue t+1 DMA early:
            const float* src = Kbh + (size_t)(t + 1) * TILE_DW;  // overlaps
            float* dst = &Ks[((t + 1) & 1) * TILE_DW];           // compute
            #pragma unroll
            for (int c = 0; c < 4; ++c)
                __builtin_amdgcn_global_load_lds(
                    (gas_float*)(src + soff[c]),
                    (las_float*)&dst[c * 2048 + wave * 256], 16, 0, 0);
        }

        // single FMA chain over d ascending per key — LOCKED order
        float v0 = 0.f, v1 = 0.f;
        #pragma unroll
        for (int dc = 0; dc < 16; ++dc) {
            const int sw = (dc ^ (lane & 7)) << 2;   // logical cols 4dc..4dc+3
            const float4 k0 = *reinterpret_cast<const float4*>(
                &buf[(lane << 6) + sw]);
            const float4 k1 = *reinterpret_cast<const float4*>(
                &buf[((64 + lane) << 6) + sw]);
            const float4 p = *reinterpret_cast<const float4*>(&Qp[dc << 2]);
            v0 = __fmaf_rn(p.x, k0.x, v0);
            v0 = __fmaf_rn(p.y, k0.y, v0);
            v0 = __fmaf_rn(p.z, k0.z, v0);
            v0 = __fmaf_rn(p.w, k0.w, v0);
            v1 = __fmaf_rn(p.x, k1.x, v1);
            v1 = __fmaf_rn(p.y, k1.y, v1);
            v1 = __fmaf_rn(p.z, k1.z, v1);
            v1 = __fmaf_rn(p.w, k1.w, v1);
        }
        // /sqrt(64) = *0.125, exact
        s[2*t]     = __fmul_rn(v0, 0.125f);
        s[2*t + 1] = __fmul_rn(v1, 0.125f);

        __syncthreads();   // drains vmcnt (t+1 loads landed under compute);
                           // publishes buf^1 for next iteration
    }

    // map scores to monotone uint space (in place)
    #pragma unroll
    for (int j = 0; j < 32; ++j)
        s[j] = __uint_as_float(mapmono(s[j]));

    // row max AND min in mapped space (max -> mrow; both -> search bounds)
    unsigned um = 0u, umin = 0xFFFFFFFFu;
    #pragma unroll
    for (int j = 0; j < 32; ++j) {
        const unsigned ub = __float_as_uint(s[j]);
        um   = um > ub ? um : ub;
        umin = umin < ub ? umin : ub;
    }
    #pragma unroll
    for (int off = 32; off; off >>= 1) {
        const unsigned o  = (unsigned)__shfl_xor((int)um, off);
        const unsigned o2 = (unsigned)__shfl_xor((int)umin, off);
        um   = um > o ? um : o;
        umin = umin < o2 ? umin : o2;
    }
    const float mrow = __uint_as_float((um & 0x80000000u) ? (um & 0x7FFFFFFFu) : ~um);

    // exact fp32 38th-largest: binary search on [min, max+1] (invariant:
    // count(u>=lo)>=38 [=2048], count(u>=hi)<38 [=0]) — identical result.
    unsigned long long lo = umin, hi = (unsigned long long)um + 1ull;
    while (hi - lo > 1ull) {
        const unsigned mid = (unsigned)((lo + hi) >> 1);
        int cnt = 0;
        #pragma unroll
        for (int j = 0; j < 32; ++j)
            cnt += (int)__popcll(__ballot(__float_as_uint(s[j]) >= mid));
        if (cnt >= U_TOP) lo = mid; else hi = mid;
    }
    const unsigned thrU = (unsigned)lo;     // mapped bits of the 38th value

    // compact kept keys (ascending key order) via ballot prefix-sum
    int base = 0; float lsum = 0.f;
    #pragma unroll
    for (int j = 0; j < 32; ++j) {
        const unsigned ub = __float_as_uint(s[j]);
        const bool keep = (ub >= thrU);     // == !(score < thr), np semantics
        const unsigned long long mk = __ballot(keep);
        if (keep) {
            const float sc = __uint_as_float((ub & 0x80000000u) ? (ub & 0x7FFFFFFFu) : ~ub);
            const float w = __expf(sc - mrow);
            const int pos = base + (int)__popcll(mk & ((1ull << lane) - 1ull));
            if (pos < 64) {
                kidx[qg][pos] = ((j >> 1) << 7) + ((j & 1) << 6) + lane;
                kwgt[qg][pos] = w;
            }
            lsum += w;
        }
        base += (int)__popcll(mk);
    }
    #pragma unroll
    for (int off = 32; off; off >>= 1) lsum += __shfl_xor(lsum, off);
    const int nk = base < 64 ? base : 64;

    // ctx[d] = (sum over kept, ascending key order) w * V[k][d] / Z
    // 8-deep load pipeline; FMA chain order preserved (ascending i)
    float acc = 0.f;
    int i = 0;
    for (; i + 8 <= nk; i += 8) {
        float wv[8], vv[8];
        #pragma unroll
        for (int u = 0; u < 8; ++u) {
            wv[u] = kwgt[qg][i + u];
            vv[u] = Vbh[(size_t)kidx[qg][i + u] * DH + lane];
        }
        #pragma unroll
        for (int u = 0; u < 8; ++u)
            acc = __fmaf_rn(wv[u], vv[u], acc);
    }
    for (; i < nk; ++i)
        acc = __fmaf_rn(kwgt[qg][i], Vbh[(size_t)kidx[qg][i] * DH + lane], acc);
    acc /= lsum;

    const int l = qt * QPB + qg;
    ctx[((size_t)(b * L_SEQ + l)) * D_MODEL + h * DH + lane] = acc;
}

extern "C" void kernel_launch(void* const* d_in, const int* in_sizes, int n_in,
                              void* d_out, int out_size, void* d_ws, size_t ws_size,
                              hipStream_t stream) {
    (void)in_sizes; (void)n_in; (void)out_size; (void)ws_size;
    const float* x  = (const float*)d_in[0];
    const float* Wq = (const float*)d_in[1];
    const float* bq = (const float*)d_in[2];
    const float* Wk = (const float*)d_in[3];
    const float* bk = (const float*)d_in[4];
    const float* Wv = (const float*)d_in[5];
    const float* bv = (const float*)d_in[6];
    const float* Wo = (const float*)d_in[7];
    const float* bo = (const float*)d_in[8];
    float* out = (float*)d_out;

    // ws: Qf | Kf | V | ctx = 4 x 16.78 MB = 67.1 MB
    const size_t NE = (size_t)B_SZ * NHEAD * L_SEQ * DH;   // 4.19e6
    float* Qf = (float*)d_ws;
    float* Kf = Qf + NE;
    float* Vw = Kf + NE;
    float* Cw = Vw + NE;

    const dim3 gqk(512, 2, 2), g(128, 8), blk(256);
    chain_gemm_qk<<<gqk, blk, 0, stream>>>(x, Wq, bq, Qf, Wk, bk, Kf);
    gemm512<1>   <<<g,   blk, 0, stream>>>(x, Wv, bv, Vw);
    attn_kernel  <<<dim3(8192), dim3(512), 0, stream>>>(Qf, Kf, Vw, Cw);
    gemm512<0>   <<<g,   blk, 0, stream>>>(Cw, Wo, bo, out);
}

// Round 24
// 1081.635 us; speedup vs baseline: 1.1263x; 1.0197x over previous
//
#include <hip/hip_runtime.h>
#include <cstdint>
#include <cstddef>

#define D_MODEL 512
#define NHEAD   8
#define DH      64
#define B_SZ    4
#define L_SEQ   2048
#define U_TOP   38          // int(5*ln(2048)) = 38
#define QPB     8           // queries per block (1 per wave)
#define KT      128         // key tile staged in LDS
#define TILE_DW (KT * DH)   // 8192 dwords

// monotone float<->uint mapping (order-preserving, exact)
__device__ __forceinline__ unsigned mapmono(float f) {
    unsigned u = __float_as_uint(f);
    return (u & 0x80000000u) ? ~u : (u | 0x80000000u);
}

typedef __attribute__((address_space(1))) const float gas_float;
typedef __attribute__((address_space(3))) float las_float;

// ---------------- fp32 GEMM: C(8192x512) = A @ W + b ----------------
// Accurate tiled version for V and the output projection (order-insensitive).
// MODE 0: C row-major (b,l,dm)   MODE 1: scatter to (b,h,l,d)
template<int MODE>
__global__ __launch_bounds__(256)
void gemm512(const float* __restrict__ A, const float* __restrict__ W,
             const float* __restrict__ bias, float* __restrict__ C)
{
    __shared__ float As[16][68];
    __shared__ float Bs[16][68];
    const int tid  = threadIdx.x;
    const int row0 = blockIdx.x * 64;
    const int col0 = blockIdx.y * 64;
    const int ty = tid >> 4, tx = tid & 15;
    float acc[4][4] = {};

    for (int kt = 0; kt < D_MODEL; kt += 16) {
        {
            const int m = tid >> 2, k = (tid & 3) << 2;
            const float4 a = *reinterpret_cast<const float4*>(
                &A[(size_t)(row0 + m) * D_MODEL + kt + k]);
            As[k + 0][m] = a.x; As[k + 1][m] = a.y;
            As[k + 2][m] = a.z; As[k + 3][m] = a.w;
        }
        {
            const int k = tid >> 4, n = (tid & 15) << 2;
            *reinterpret_cast<float4*>(&Bs[k][n]) =
                *reinterpret_cast<const float4*>(
                    &W[(size_t)(kt + k) * D_MODEL + col0 + n]);
        }
        __syncthreads();
        #pragma unroll
        for (int kk = 0; kk < 16; ++kk) {
            const float4 a4 = *reinterpret_cast<const float4*>(&As[kk][ty << 2]);
            const float4 b4 = *reinterpret_cast<const float4*>(&Bs[kk][tx << 2]);
            const float av[4] = {a4.x, a4.y, a4.z, a4.w};
            const float bv[4] = {b4.x, b4.y, b4.z, b4.w};
            #pragma unroll
            for (int i = 0; i < 4; ++i)
                #pragma unroll
                for (int j = 0; j < 4; ++j)
                    acc[i][j] += av[i] * bv[j];
        }
        __syncthreads();
    }

    #pragma unroll
    for (int i = 0; i < 4; ++i) {
        const int r = row0 + (ty << 2) + i;
        const int cb = col0 + (tx << 2);
        float4 v;
        v.x = acc[i][0] + bias[cb + 0];
        v.y = acc[i][1] + bias[cb + 1];
        v.z = acc[i][2] + bias[cb + 2];
        v.w = acc[i][3] + bias[cb + 3];
        if (MODE == 0) {
            *reinterpret_cast<float4*>(&C[(size_t)r * D_MODEL + cb]) = v;
        } else {
            const int b = r >> 11, l = r & (L_SEQ - 1);
            const int h = cb >> 6, d = cb & 63;
            *reinterpret_cast<float4*>(
                &C[(size_t)((b * NHEAD + h) * L_SEQ + l) * DH + d]) = v;
        }
    }
}

// ----- np-replica GEMM for Q,K: SINGLE K-panel sequential FMA chain -----
// (LOCKED arithmetic — passed round 9. Per C element: ONE fp32 accumulator,
// FMA over k=0..511 ascending, then one fp32 bias add.)
// Fused: blockIdx.z = 0 -> (Wq,bq,OutQ), 1 -> (Wk,bk,OutK).
__global__ __launch_bounds__(256)
void chain_gemm_qk(const float* __restrict__ x,
                   const float* __restrict__ Wq, const float* __restrict__ bq,
                   float* __restrict__ OutQ,
                   const float* __restrict__ Wk, const float* __restrict__ bk,
                   float* __restrict__ OutK)
{
    const float* __restrict__ W    = blockIdx.z ? Wk : Wq;
    const float* __restrict__ bias = blockIdx.z ? bk : bq;
    float* __restrict__ Out        = blockIdx.z ? OutK : OutQ;

    const int tid  = threadIdx.x;
    const int col  = blockIdx.y * 256 + tid;        // 0..511
    const int row0 = blockIdx.x * 16;               // 16 rows per block

    float acc[16];
    #pragma unroll
    for (int r = 0; r < 16; ++r) acc[r] = 0.f;

    for (int k = 0; k < D_MODEL; k += 4) {          // one panel: k = 0..511
        const float w0 = W[(size_t)(k + 0) * D_MODEL + col];
        const float w1 = W[(size_t)(k + 1) * D_MODEL + col];
        const float w2 = W[(size_t)(k + 2) * D_MODEL + col];
        const float w3 = W[(size_t)(k + 3) * D_MODEL + col];
        #pragma unroll
        for (int r = 0; r < 16; ++r) {
            const float4 xv = *reinterpret_cast<const float4*>(
                &x[(size_t)(row0 + r) * D_MODEL + k]);
            acc[r] = __fmaf_rn(xv.x, w0, acc[r]);
            acc[r] = __fmaf_rn(xv.y, w1, acc[r]);
            acc[r] = __fmaf_rn(xv.z, w2, acc[r]);
            acc[r] = __fmaf_rn(xv.w, w3, acc[r]);
        }
    }

    const float bc = bias[col];
    const int h = col >> 6, d = col & 63;
    #pragma unroll
    for (int r = 0; r < 16; ++r) {
        const int row = row0 + r;
        const int b = row >> 11, l = row & (L_SEQ - 1);
        Out[((size_t)((b * NHEAD + h) * L_SEQ + l)) * DH + d] =
            __fadd_rn(acc[r], bc);
    }
}

// ---- attention: BLAS-chain scores (LOCKED bits) -> exact fp32 top-38 ----
// r24 = r23 + M38-seeded selection search (bit-identical result):
//  * M38 = 38th largest of the 64 per-lane maxima. Valid exact lower
//    bound: the 38 largest lane-maxima are 38 DISTINCT elements >= M38
//    => count(>=M38) >= 38 => P(M38)=true, and M38 <= thr <= rowmax.
//    Computed with a 1-cmp-per-iter search (~300cyc); main 32-cmp search
//    then spans only the top-40 value spread (~2^21 -> ~21 iters vs 31).
//  * dbuf global_load_lds staging (r23-proven), scalar Q, XCD swizzle.
__global__ __launch_bounds__(512, 4)
void attn_kernel(const float* __restrict__ Q, const float* __restrict__ K,
                 const float* __restrict__ V, float* __restrict__ ctx)
{
    __shared__ float Ks[2 * TILE_DW];      // 64 KB dbuf; slot s of each buf
                                           // holds K[s>>6][(s&63)^(((s>>6)&7)<<2)]
    __shared__ int   kidx[QPB][64];        // 2 KB  kept keys (ascending)
    __shared__ float kwgt[QPB][64];        // 2 KB  kept exp-weights

    // XCD swizzle: all 256 q-tiles of a (b,h) on one XCD (K/V L2-resident)
    const int bid = blockIdx.x;
    const int xcd = bid & 7, jrem = bid >> 3;
    const int bh  = xcd * 4 + (jrem >> 8);   // 0..31
    const int qt  = jrem & 255;              // 0..255
    const int b   = bh >> 3, h = bh & 7;

    const float* __restrict__ Qbh = Q + (size_t)bh * L_SEQ * DH;
    const float* __restrict__ Kbh = K + (size_t)bh * L_SEQ * DH;
    const float* __restrict__ Vbh = V + (size_t)bh * L_SEQ * DH;

    const int tid = threadIdx.x;
    const int wave = tid >> 6, lane = tid & 63;
    const int qg = wave;                     // one query per wave

    // wave-uniform Q row pointer, forced scalar -> s_load path
    const int qrow = __builtin_amdgcn_readfirstlane(qt * QPB + wave);
    const float* __restrict__ Qp = Qbh + (size_t)qrow * DH;

    // pre-swizzled global source offsets (tile-invariant, 4 chunks)
    int soff[4];
    #pragma unroll
    for (int c = 0; c < 4; ++c) {
        const int f = c * 2048 + tid * 4;
        const int r = f >> 6, col = f & 63;
        soff[c] = (r << 6) + (col ^ ((r & 7) << 2));
    }

    // prologue: DMA tile 0 into buf0, publish
    #pragma unroll
    for (int c = 0; c < 4; ++c)
        __builtin_amdgcn_global_load_lds(
            (gas_float*)(Kbh + soff[c]),
            (las_float*)&Ks[c * 2048 + wave * 256], 16, 0, 0);
    __syncthreads();

    float s[32];

    #pragma unroll
    for (int t = 0; t < L_SEQ / KT; ++t) {        // 16 tiles, fully unrolled
        const float* buf = &Ks[(t & 1) * TILE_DW];

        if (t < L_SEQ / KT - 1) {                  // issue t+1 DMA early:
            const float* src = Kbh + (size_t)(t + 1) * TILE_DW;  // overlaps
            float* dst = &Ks[((t + 1) & 1) * TILE_DW];           // compute
            #pragma unroll
            for (int c = 0; c < 4; ++c)
                __builtin_amdgcn_global_load_lds(
                    (gas_float*)(src + soff[c]),
                    (las_float*)&dst[c * 2048 + wave * 256], 16, 0, 0);
        }

        // single FMA chain over d ascending per key — LOCKED order
        float v0 = 0.f, v1 = 0.f;
        #pragma unroll
        for (int dc = 0; dc < 16; ++dc) {
            const int sw = (dc ^ (lane & 7)) << 2;   // logical cols 4dc..4dc+3
            const float4 k0 = *reinterpret_cast<const float4*>(
                &buf[(lane << 6) + sw]);
            const float4 k1 = *reinterpret_cast<const float4*>(
                &buf[((64 + lane) << 6) + sw]);
            const float4 p = *reinterpret_cast<const float4*>(&Qp[dc << 2]);
            v0 = __fmaf_rn(p.x, k0.x, v0);
            v0 = __fmaf_rn(p.y, k0.y, v0);
            v0 = __fmaf_rn(p.z, k0.z, v0);
            v0 = __fmaf_rn(p.w, k0.w, v0);
            v1 = __fmaf_rn(p.x, k1.x, v1);
            v1 = __fmaf_rn(p.y, k1.y, v1);
            v1 = __fmaf_rn(p.z, k1.z, v1);
            v1 = __fmaf_rn(p.w, k1.w, v1);
        }
        // /sqrt(64) = *0.125, exact
        s[2*t]     = __fmul_rn(v0, 0.125f);
        s[2*t + 1] = __fmul_rn(v1, 0.125f);

        __syncthreads();   // drains vmcnt (t+1 loads landed under compute);
                           // publishes buf^1 for next iteration
    }

    // map scores to monotone uint space (in place)
    #pragma unroll
    for (int j = 0; j < 32; ++j)
        s[j] = __uint_as_float(mapmono(s[j]));

    // per-lane max; wave max (-> mrow)
    unsigned plm = 0u;
    #pragma unroll
    for (int j = 0; j < 32; ++j) {
        const unsigned ub = __float_as_uint(s[j]);
        plm = plm > ub ? plm : ub;
    }
    unsigned um = plm;
    #pragma unroll
    for (int off = 32; off; off >>= 1) {
        const unsigned o = (unsigned)__shfl_xor((int)um, off);
        um = um > o ? um : o;
    }
    const float mrow = __uint_as_float((um & 0x80000000u) ? (um & 0x7FFFFFFFu) : ~um);

    // M38 = 38th largest of the 64 per-lane maxima (1 cmp/iter, cheap).
    // Exact lower bound for the 38th largest overall (38 distinct
    // elements — the top-38 lane maxima — are >= M38).
    unsigned long long l2 = 0ull, h2 = 0x100000000ull;
    while (h2 - l2 > 1ull) {
        const unsigned mid = (unsigned)((l2 + h2) >> 1);
        if ((int)__popcll(__ballot(plm >= mid)) >= U_TOP) l2 = mid; else h2 = mid;
    }

    // exact fp32 38th-largest: binary search on [M38, max+1] (invariant:
    // count(u>=lo)>=38, count(u>=hi)<38) — identical result, fewer iters.
    unsigned long long lo = l2, hi = (unsigned long long)um + 1ull;
    while (hi - lo > 1ull) {
        const unsigned mid = (unsigned)((lo + hi) >> 1);
        int cnt = 0;
        #pragma unroll
        for (int j = 0; j < 32; ++j)
            cnt += (int)__popcll(__ballot(__float_as_uint(s[j]) >= mid));
        if (cnt >= U_TOP) lo = mid; else hi = mid;
    }
    const unsigned thrU = (unsigned)lo;     // mapped bits of the 38th value

    // compact kept keys (ascending key order) via ballot prefix-sum
    int base = 0; float lsum = 0.f;
    #pragma unroll
    for (int j = 0; j < 32; ++j) {
        const unsigned ub = __float_as_uint(s[j]);
        const bool keep = (ub >= thrU);     // == !(score < thr), np semantics
        const unsigned long long mk = __ballot(keep);
        if (keep) {
            const float sc = __uint_as_float((ub & 0x80000000u) ? (ub & 0x7FFFFFFFu) : ~ub);
            const float w = __expf(sc - mrow);
            const int pos = base + (int)__popcll(mk & ((1ull << lane) - 1ull));
            if (pos < 64) {
                kidx[qg][pos] = ((j >> 1) << 7) + ((j & 1) << 6) + lane;
                kwgt[qg][pos] = w;
            }
            lsum += w;
        }
        base += (int)__popcll(mk);
    }
    #pragma unroll
    for (int off = 32; off; off >>= 1) lsum += __shfl_xor(lsum, off);
    const int nk = base < 64 ? base : 64;

    // ctx[d] = (sum over kept, ascending key order) w * V[k][d] / Z
    // 8-deep load pipeline; FMA chain order preserved (ascending i)
    float acc = 0.f;
    int i = 0;
    for (; i + 8 <= nk; i += 8) {
        float wv[8], vv[8];
        #pragma unroll
        for (int u = 0; u < 8; ++u) {
            wv[u] = kwgt[qg][i + u];
            vv[u] = Vbh[(size_t)kidx[qg][i + u] * DH + lane];
        }
        #pragma unroll
        for (int u = 0; u < 8; ++u)
            acc = __fmaf_rn(wv[u], vv[u], acc);
    }
    for (; i < nk; ++i)
        acc = __fmaf_rn(kwgt[qg][i], Vbh[(size_t)kidx[qg][i] * DH + lane], acc);
    acc /= lsum;

    const int l = qt * QPB + qg;
    ctx[((size_t)(b * L_SEQ + l)) * D_MODEL + h * DH + lane] = acc;
}

extern "C" void kernel_launch(void* const* d_in, const int* in_sizes, int n_in,
                              void* d_out, int out_size, void* d_ws, size_t ws_size,
                              hipStream_t stream) {
    (void)in_sizes; (void)n_in; (void)out_size; (void)ws_size;
    const float* x  = (const float*)d_in[0];
    const float* Wq = (const float*)d_in[1];
    const float* bq = (const float*)d_in[2];
    const float* Wk = (const float*)d_in[3];
    const float* bk = (const float*)d_in[4];
    const float* Wv = (const float*)d_in[5];
    const float* bv = (const float*)d_in[6];
    const float* Wo = (const float*)d_in[7];
    const float* bo = (const float*)d_in[8];
    float* out = (float*)d_out;

    // ws: Qf | Kf | V | ctx = 4 x 16.78 MB = 67.1 MB
    const size_t NE = (size_t)B_SZ * NHEAD * L_SEQ * DH;   // 4.19e6
    float* Qf = (float*)d_ws;
    float* Kf = Qf + NE;
    float* Vw = Kf + NE;
    float* Cw = Vw + NE;

    const dim3 gqk(512, 2, 2), g(128, 8), blk(256);
    chain_gemm_qk<<<gqk, blk, 0, stream>>>(x, Wq, bq, Qf, Wk, bk, Kf);
    gemm512<1>   <<<g,   blk, 0, stream>>>(x, Wv, bv, Vw);
    attn_kernel  <<<dim3(8192), dim3(512), 0, stream>>>(Qf, Kf, Vw, Cw);
    gemm512<0>   <<<g,   blk, 0, stream>>>(Cw, Wo, bo, out);
}